// Round 1
// baseline (1052.629 us; speedup 1.0000x reference)
//
#include <hip/hip_runtime.h>
#include <math.h>

#define NB 1024
#define NF 36
#define ED 256
#define NK 8
#define NN2 1296   // 36*36
#define QPK 162    // 1296/8

// Repack W[k][c][d] (row-major) -> Wt4[(k*64 + d4)*256 + c] = float4 of W[k][c][4*d4 .. 4*d4+3]
// so phase-1 reads (fixed d4, lanes over c) are coalesced.
__global__ __launch_bounds__(256) void prep_w_kernel(const float* __restrict__ W,
                                                     float4* __restrict__ Wt4) {
    int idx = blockIdx.x * 256 + threadIdx.x;   // [0, NK*64*256)
    int c  = idx & 255;
    int d4 = (idx >> 8) & 63;
    int k  = idx >> 14;
    const float* src = W + ((((size_t)k << 8) | c) << 8) + (d4 << 2);
    Wt4[idx] = make_float4(src[0], src[1], src[2], src[3]);
}

__global__ __launch_bounds__(256, 2) void ntn_main(
    const float* __restrict__ texts, const float4* __restrict__ Wt4,
    const float* __restrict__ Wb,
    const float* __restrict__ V1w, const float* __restrict__ V1b,
    const float* __restrict__ V2w, const float* __restrict__ V2b,
    const float* __restrict__ Uw,  const float* __restrict__ Ubp,
    float* __restrict__ logits)
{
    __shared__ __align__(16) float Xs[NF][260];   // row stride 260 floats: 16B-aligned rows, bank-skewed
    __shared__ __align__(16) float Wh[NF][132];   // half-width Wx staging (c-chunk of 128) / later reused as Ts
    __shared__ float v1s[NF], v2s[NF], Uws[8];

    const int k = blockIdx.x;
    const int b = blockIdx.y;
    const int t = threadIdx.x;

    // ---- load X_b into LDS (coalesced: thread t = column d=t) ----
    const float* xb = texts + (size_t)b * NF * ED;
    #pragma unroll
    for (int j = 0; j < NF; ++j) Xs[j][t] = xb[j * ED + t];
    if (t < 8) Uws[t] = Uw[t];
    __syncthreads();

    // ---- v1/v2 (small dots, subset of threads; wave-uniform-ish branches) ----
    if (t < NF) {
        const float4* vp = (const float4*)(V1w + k * ED);
        const float4* xr = (const float4*)(&Xs[t][0]);
        float s = 0.f;
        #pragma unroll 8
        for (int d4 = 0; d4 < 64; ++d4) {
            float4 a = vp[d4], x = xr[d4];
            s += a.x * x.x + a.y * x.y + a.z * x.z + a.w * x.w;
        }
        v1s[t] = s + V1b[k];
    } else if (t >= 64 && t < 64 + NF) {
        int m = t - 64;
        const float4* vp = (const float4*)(V2w + k * ED);
        const float4* xr = (const float4*)(&Xs[m][0]);
        float s = 0.f;
        #pragma unroll 8
        for (int d4 = 0; d4 < 64; ++d4) {
            float4 a = vp[d4], x = xr[d4];
            s += a.x * x.x + a.y * x.y + a.z * x.z + a.w * x.w;
        }
        v2s[m] = s + V2b[k];
    }

    // ---- phase 1: Wx[n][c=t] for all n (thread t owns one c-column) ----
    float acc[NF];
    {
        float wbv = Wb[k * ED + t];
        #pragma unroll
        for (int n = 0; n < NF; ++n) acc[n] = wbv;
        const float4* wp = Wt4 + (size_t)k * 64 * 256 + t;
        for (int d4 = 0; d4 < 64; ++d4) {
            float4 w4 = wp[(size_t)d4 * 256];     // coalesced (lanes over c)
            const int dc = d4 << 2;
            #pragma unroll
            for (int n = 0; n < NF; ++n) {
                float4 x4 = *(const float4*)(&Xs[n][dc]);   // broadcast (same addr all lanes)
                acc[n] = fmaf(w4.x, x4.x,
                         fmaf(w4.y, x4.y,
                         fmaf(w4.z, x4.z,
                         fmaf(w4.w, x4.w, acc[n]))));
            }
        }
    }

    // ---- phase 2: S[n,m] = sum_c Wx[n,c] * X[m,c], in two c-halves via Wh ----
    float Sacc[6] = {0.f, 0.f, 0.f, 0.f, 0.f, 0.f};

    __syncthreads();
    if (t < 128) {
        #pragma unroll
        for (int n = 0; n < NF; ++n) Wh[n][t] = acc[n];
    }
    __syncthreads();
    #pragma unroll
    for (int j = 0; j < 6; ++j) {
        int idx = t + j * 256;
        if (idx < NN2) {
            int n = idx / NF, m = idx % NF;
            const float4* wr = (const float4*)(&Wh[n][0]);
            const float4* xr = (const float4*)(&Xs[m][0]);
            float s = 0.f;
            #pragma unroll 8
            for (int c4 = 0; c4 < 32; ++c4) {
                float4 a = wr[c4], x = xr[c4];
                s += a.x * x.x + a.y * x.y + a.z * x.z + a.w * x.w;
            }
            Sacc[j] += s;
        }
    }
    __syncthreads();
    if (t >= 128) {
        #pragma unroll
        for (int n = 0; n < NF; ++n) Wh[n][t - 128] = acc[n];
    }
    __syncthreads();
    #pragma unroll
    for (int j = 0; j < 6; ++j) {
        int idx = t + j * 256;
        if (idx < NN2) {
            int n = idx / NF, m = idx % NF;
            const float4* wr = (const float4*)(&Wh[n][0]);
            const float4* xr = (const float4*)(&Xs[m][128]);
            float s = 0.f;
            #pragma unroll 8
            for (int c4 = 0; c4 < 32; ++c4) {
                float4 a = wr[c4], x = xr[c4];
                s += a.x * x.x + a.y * x.y + a.z * x.z + a.w * x.w;
            }
            Sacc[j] += s;
        }
    }
    __syncthreads();

    // ---- epilogue: T = tanh(S + v1[n] + v2[m]) into Ts (alias Wh), then U-contraction ----
    float* Ts = &Wh[0][0];   // 1296 floats fit in Wh (19008 B)
    #pragma unroll
    for (int j = 0; j < 6; ++j) {
        int idx = t + j * 256;
        if (idx < NN2) {
            int n = idx / NF, m = idx % NF;
            Ts[idx] = tanhf(Sacc[j] + v1s[n] + v2s[m]);
        }
    }
    __syncthreads();
    // logits[b, k*162 + q] = Ub + sum_j Uw[j] * T_lin[q*8 + j]
    if (t < QPK) {
        float lg = Ubp[0];
        #pragma unroll
        for (int j = 0; j < 8; ++j) lg += Uws[j] * Ts[t * 8 + j];
        logits[(size_t)b * NN2 + k * QPK + t] = lg;
    }
}

// In-place row softmax over d_out: one 64-thread block per output row (b, n_o).
__global__ __launch_bounds__(64) void softmax_rows(float* __restrict__ out) {
    int row = blockIdx.x;            // b*36 + n_o
    int t = threadIdx.x;
    float* p = out + (size_t)row * NF;
    float v = (t < NF) ? p[t] : -INFINITY;
    float mx = v;
    #pragma unroll
    for (int off = 32; off > 0; off >>= 1) mx = fmaxf(mx, __shfl_xor(mx, off));
    float e = (t < NF) ? __expf(v - mx) : 0.f;
    float sm = e;
    #pragma unroll
    for (int off = 32; off > 0; off >>= 1) sm += __shfl_xor(sm, off);
    if (t < NF) p[t] = e / sm;
}

extern "C" void kernel_launch(void* const* d_in, const int* in_sizes, int n_in,
                              void* d_out, int out_size, void* d_ws, size_t ws_size,
                              hipStream_t stream) {
    const float* texts = (const float*)d_in[0];
    const float* W     = (const float*)d_in[1];
    const float* Wb    = (const float*)d_in[2];
    const float* V1w   = (const float*)d_in[3];
    const float* V1b   = (const float*)d_in[4];
    const float* V2w   = (const float*)d_in[5];
    const float* V2b   = (const float*)d_in[6];
    const float* Uw    = (const float*)d_in[7];
    const float* Ub    = (const float*)d_in[8];

    float4* Wt4   = (float4*)d_ws;         // NK*64*256 float4 = 2 MiB
    float* logits = (float*)d_out;         // [NB, 1296] built in place, then softmaxed in place

    prep_w_kernel<<<NK * 64, 256, 0, stream>>>(W, Wt4);
    ntn_main<<<dim3(NK, NB), 256, 0, stream>>>(texts, Wt4, Wb, V1w, V1b, V2w, V2b, Uw, Ub, logits);
    softmax_rows<<<NB * NF, 64, 0, stream>>>(logits);
}

// Round 2
// 486.029 us; speedup vs baseline: 2.1658x; 2.1658x over previous
//
#include <hip/hip_runtime.h>
#include <math.h>

#define NB 1024
#define NF 36
#define ED 256
#define NK 8
#define NN2 1296   // 36*36
#define QPK 162    // 1296/8

typedef _Float16 f16;
typedef f16 f16x8 __attribute__((ext_vector_type(8)));
typedef float f32x4 __attribute__((ext_vector_type(4)));

#define XSTR 264    // f16 elems per X row (256 + 8 pad -> 2-way-max LDS banking)
#define WXSTR 136   // f16 elems per Wx half-row (128 + 8 pad)
#define XROWS 84    // 72 real rows (2 b) + pad so b1's rt=2 tile reads stay in range

// LDS byte offsets
#define XH_OFF   0
#define XL_OFF   (XH_OFF + XROWS*XSTR*2)     // 44352
#define WXH_OFF  (XL_OFF + XROWS*XSTR*2)     // 88704
#define WXL_OFF  (WXH_OFF + XROWS*WXSTR*2)   // 111552
#define V1_OFF   (WXL_OFF + XROWS*WXSTR*2)   // 134400
#define V2_OFF   (V1_OFF + 72*4)             // 134688
#define U_OFF    (V2_OFF + 72*4)             // 134976
#define SMEM_BYTES (U_OFF + 64)              // 135040 (~132 KB, needs dynamic-LDS opt-in)

__device__ __forceinline__ f32x4 mfma16(f16x8 a, f16x8 b, f32x4 c) {
    return __builtin_amdgcn_mfma_f32_16x16x32_f16(a, b, c, 0, 0, 0);
}

// Pack W[k][c][d] -> B-fragment order, scaled by 16 (keeps W-lo out of fp16
// denormal range; |W|<=0.108 so |W_lo| would be < fp16 min normal).
// Wf[(k*16+ct)*8+kc][lane=quad*16+(c&15)][j] = 16*W[k][ct*16+(c&15)][kc*32+quad*8+j]
__global__ __launch_bounds__(256) void prep_w(const float* __restrict__ W,
                                              f16x8* __restrict__ WfH,
                                              f16x8* __restrict__ WfL) {
    int idx = blockIdx.x * 256 + threadIdx.x;   // 65536 total
    int dox = idx & 31;            // d-octet
    int c   = (idx >> 5) & 255;
    int k   = idx >> 13;
    const float* src = W + ((size_t)(k * 256 + c)) * 256 + dox * 8;
    float4 a = *(const float4*)src;
    float4 b = *(const float4*)(src + 4);
    float v[8] = {a.x, a.y, a.z, a.w, b.x, b.y, b.z, b.w};
    f16x8 hi, lo;
    #pragma unroll
    for (int j = 0; j < 8; ++j) {
        float sv = v[j] * 16.0f;
        f16 h = (f16)sv;
        hi[j] = h;
        lo[j] = (f16)(sv - (float)h);
    }
    int kc = dox >> 2, qd = dox & 3, ct = c >> 4;
    int fr = ((k * 16 + ct) * 8 + kc) * 64 + qd * 16 + (c & 15);
    WfH[fr] = hi;
    WfL[fr] = lo;
}

__global__ __launch_bounds__(256, 1) void ntn_main(
    const float* __restrict__ texts,
    const f16x8* __restrict__ WfH, const f16x8* __restrict__ WfL,
    const float* __restrict__ Wb,
    const float* __restrict__ V1w, const float* __restrict__ V1b,
    const float* __restrict__ V2w, const float* __restrict__ V2b,
    const float* __restrict__ Uw,  const float* __restrict__ Ubp,
    float* __restrict__ logits)
{
    extern __shared__ char smem[];
    f16*   Xh  = (f16*)(smem + XH_OFF);
    f16*   Xl  = (f16*)(smem + XL_OFF);
    f16*   Wxh = (f16*)(smem + WXH_OFF);
    f16*   Wxl = (f16*)(smem + WXL_OFF);
    float* v1s = (float*)(smem + V1_OFF);
    float* v2s = (float*)(smem + V2_OFF);
    float* Uws = (float*)(smem + U_OFF);

    const int k     = blockIdx.x;
    const int bpair = blockIdx.y;
    const int t     = threadIdx.x;
    const int wave  = t >> 6;
    const int lane  = t & 63;
    const int quad  = lane >> 4;
    const int l15   = lane & 15;

    // ---- load X (2 b's = 72 rows), split hi/lo into LDS ----
    const float* xb = texts + (size_t)bpair * 2 * NF * ED;
    #pragma unroll 4
    for (int r = 0; r < 72; ++r) {
        float v = xb[r * ED + t];
        f16 h = (f16)v;
        Xh[r * XSTR + t] = h;
        Xl[r * XSTR + t] = (f16)(v - (float)h);
    }
    if (t < 264) {
        #pragma unroll
        for (int r = 72; r < XROWS; ++r) { Xh[r * XSTR + t] = (f16)0.f; Xl[r * XSTR + t] = (f16)0.f; }
    }
    if (t < 8) Uws[t] = Uw[t];
    if (t == 8) Uws[8] = Ubp[0];
    __syncthreads();

    // ---- v1/v2 (fp32 dots via hi+lo reconstruction) ----
    if (t < 72) {
        const float4* vp = (const float4*)(V1w + k * ED);
        const f16* xh = Xh + t * XSTR;
        const f16* xl = Xl + t * XSTR;
        float s = 0.f;
        #pragma unroll 4
        for (int d8 = 0; d8 < 32; ++d8) {
            f16x8 h8 = *(const f16x8*)(xh + d8 * 8);
            f16x8 l8 = *(const f16x8*)(xl + d8 * 8);
            float4 a0 = vp[2 * d8], a1 = vp[2 * d8 + 1];
            s += a0.x * ((float)h8[0] + (float)l8[0]) + a0.y * ((float)h8[1] + (float)l8[1])
               + a0.z * ((float)h8[2] + (float)l8[2]) + a0.w * ((float)h8[3] + (float)l8[3])
               + a1.x * ((float)h8[4] + (float)l8[4]) + a1.y * ((float)h8[5] + (float)l8[5])
               + a1.z * ((float)h8[6] + (float)l8[6]) + a1.w * ((float)h8[7] + (float)l8[7]);
        }
        v1s[t] = s + V1b[k];
    } else if (t >= 128 && t < 200) {
        const int m = t - 128;
        const float4* vp = (const float4*)(V2w + k * ED);
        const f16* xh = Xh + m * XSTR;
        const f16* xl = Xl + m * XSTR;
        float s = 0.f;
        #pragma unroll 4
        for (int d8 = 0; d8 < 32; ++d8) {
            f16x8 h8 = *(const f16x8*)(xh + d8 * 8);
            f16x8 l8 = *(const f16x8*)(xl + d8 * 8);
            float4 a0 = vp[2 * d8], a1 = vp[2 * d8 + 1];
            s += a0.x * ((float)h8[0] + (float)l8[0]) + a0.y * ((float)h8[1] + (float)l8[1])
               + a0.z * ((float)h8[2] + (float)l8[2]) + a0.w * ((float)h8[3] + (float)l8[3])
               + a1.x * ((float)h8[4] + (float)l8[4]) + a1.y * ((float)h8[5] + (float)l8[5])
               + a1.z * ((float)h8[6] + (float)l8[6]) + a1.w * ((float)h8[7] + (float)l8[7]);
        }
        v2s[m] = s + V2b[k];
    }

    // ---- phase-2 accumulators persist across the two c-halves ----
    f32x4 sacc[3][2];
    #pragma unroll
    for (int i = 0; i < 3; ++i)
        #pragma unroll
        for (int j = 0; j < 2; ++j)
            sacc[i][j] = (f32x4){0.f, 0.f, 0.f, 0.f};

    const f16x8* WfHk = WfH + (size_t)k * 16 * 8 * 64;
    const f16x8* WfLk = WfL + (size_t)k * 16 * 8 * 64;
    const int bp  = wave >> 1;
    const int odd = wave & 1;
    const int nct = odd ? 1 : 2;

    for (int h = 0; h < 2; ++h) {
        // ===== phase 1: Wx[:, c-half] = X * W[k]^T (split: AhBh + AhBl + AlBh) =====
        f32x4 acc[5][2];
        #pragma unroll
        for (int i = 0; i < 5; ++i) { acc[i][0] = (f32x4){0,0,0,0}; acc[i][1] = (f32x4){0,0,0,0}; }
        const int ct0 = h * 8 + wave;
        const int ct1 = ct0 + 4;
        #pragma unroll 2
        for (int kc = 0; kc < 8; ++kc) {
            const int aoff = kc * 32 + quad * 8;
            f16x8 ah[5], al[5];
            #pragma unroll
            for (int rt = 0; rt < 5; ++rt) {
                const int row = rt * 16 + l15;
                ah[rt] = *(const f16x8*)(Xh + row * XSTR + aoff);
                al[rt] = *(const f16x8*)(Xl + row * XSTR + aoff);
            }
            f16x8 bh0 = WfHk[(ct0 * 8 + kc) * 64 + lane];
            f16x8 bl0 = WfLk[(ct0 * 8 + kc) * 64 + lane];
            f16x8 bh1 = WfHk[(ct1 * 8 + kc) * 64 + lane];
            f16x8 bl1 = WfLk[(ct1 * 8 + kc) * 64 + lane];
            #pragma unroll
            for (int rt = 0; rt < 5; ++rt) {
                acc[rt][0] = mfma16(ah[rt], bh0, acc[rt][0]);
                acc[rt][0] = mfma16(ah[rt], bl0, acc[rt][0]);
                acc[rt][0] = mfma16(al[rt], bh0, acc[rt][0]);
                acc[rt][1] = mfma16(ah[rt], bh1, acc[rt][1]);
                acc[rt][1] = mfma16(ah[rt], bl1, acc[rt][1]);
                acc[rt][1] = mfma16(al[rt], bh1, acc[rt][1]);
            }
        }
        __syncthreads();   // prior phase-2 reads of Wx are done before we overwrite
        // ---- unscale (W was *16), add bias, split Wx hi/lo into LDS ----
        {
            const float wb0 = Wb[k * ED + ct0 * 16 + l15];
            const float wb1 = Wb[k * ED + ct1 * 16 + l15];
            #pragma unroll
            for (int rt = 0; rt < 5; ++rt) {
                #pragma unroll
                for (int j2 = 0; j2 < 2; ++j2) {
                    const float wb = j2 ? wb1 : wb0;
                    const int cl = (j2 ? (wave + 4) : wave) * 16 + l15;
                    #pragma unroll
                    for (int r = 0; r < 4; ++r) {
                        const int row = rt * 16 + quad * 4 + r;
                        float v = acc[rt][j2][r] * 0.0625f + wb;
                        f16 hh = (f16)v;
                        Wxh[row * WXSTR + cl] = hh;
                        Wxl[row * WXSTR + cl] = (f16)(v - (float)hh);
                    }
                }
            }
        }
        if (t < 136) {   // zero pad rows so b1's rt=2 A-frag reads are finite
            #pragma unroll
            for (int r = 80; r < XROWS; ++r) { Wxh[r * WXSTR + t] = (f16)0.f; Wxl[r * WXSTR + t] = (f16)0.f; }
        }
        __syncthreads();

        // ===== phase 2: S += Wx[:, half] * X[:, half]^T (split) =====
        #pragma unroll
        for (int kc2 = 0; kc2 < 4; ++kc2) {
            const int coff = kc2 * 32 + quad * 8;
            f16x8 pah[3], pal[3];
            #pragma unroll
            for (int rt = 0; rt < 3; ++rt) {
                const int row = bp * NF + rt * 16 + l15;
                pah[rt] = *(const f16x8*)(Wxh + row * WXSTR + coff);
                pal[rt] = *(const f16x8*)(Wxl + row * WXSTR + coff);
            }
            for (int ctl = 0; ctl < nct; ++ctl) {
                const int ct2 = odd ? 2 : ctl;
                const int brow = bp * NF + ct2 * 16 + l15;
                f16x8 pbh = *(const f16x8*)(Xh + brow * XSTR + h * 128 + coff);
                f16x8 pbl = *(const f16x8*)(Xl + brow * XSTR + h * 128 + coff);
                #pragma unroll
                for (int rt = 0; rt < 3; ++rt) {
                    sacc[rt][ctl] = mfma16(pah[rt], pbh, sacc[rt][ctl]);
                    sacc[rt][ctl] = mfma16(pah[rt], pbl, sacc[rt][ctl]);
                    sacc[rt][ctl] = mfma16(pal[rt], pbh, sacc[rt][ctl]);
                }
            }
        }
    }

    // ===== epilogue: T = tanh(S + v1 + v2) -> Ts (overlays Wx), then U-dot =====
    __syncthreads();
    float* Ts = (float*)(smem + WXH_OFF);   // 2*1296 floats, fits in Wxh region
    for (int ctl = 0; ctl < nct; ++ctl) {
        const int ct2 = odd ? 2 : ctl;
        const int m = ct2 * 16 + l15;
        if (m < NF) {
            #pragma unroll
            for (int rt = 0; rt < 3; ++rt) {
                #pragma unroll
                for (int r = 0; r < 4; ++r) {
                    const int n = rt * 16 + quad * 4 + r;
                    if (n < NF) {
                        float sv = sacc[rt][ctl][r] + v1s[bp * NF + n] + v2s[bp * NF + m];
                        float e = __expf(2.f * sv);
                        Ts[bp * NN2 + n * NF + m] = 1.f - 2.f / (e + 1.f);
                    }
                }
            }
        }
    }
    __syncthreads();
    for (int q2 = t; q2 < 2 * QPK; q2 += 256) {
        const int bp2 = q2 / QPK;
        const int q = q2 - bp2 * QPK;
        const float* tp = Ts + bp2 * NN2 + q * 8;
        float lg = Uws[8];
        #pragma unroll
        for (int j = 0; j < 8; ++j) lg += Uws[j] * tp[j];
        logits[((size_t)(bpair * 2 + bp2)) * NN2 + k * QPK + q] = lg;
    }
}

// In-place row softmax: one 64-thread block per output row (b, n).
__global__ __launch_bounds__(64) void softmax_rows(float* __restrict__ out) {
    int row = blockIdx.x;
    int t = threadIdx.x;
    float* p = out + (size_t)row * NF;
    float v = (t < NF) ? p[t] : -INFINITY;
    float mx = v;
    #pragma unroll
    for (int off = 32; off > 0; off >>= 1) mx = fmaxf(mx, __shfl_xor(mx, off));
    float e = (t < NF) ? __expf(v - mx) : 0.f;
    float sm = e;
    #pragma unroll
    for (int off = 32; off > 0; off >>= 1) sm += __shfl_xor(sm, off);
    if (t < NF) p[t] = e / sm;
}

extern "C" void kernel_launch(void* const* d_in, const int* in_sizes, int n_in,
                              void* d_out, int out_size, void* d_ws, size_t ws_size,
                              hipStream_t stream) {
    const float* texts = (const float*)d_in[0];
    const float* W     = (const float*)d_in[1];
    const float* Wb    = (const float*)d_in[2];
    const float* V1w   = (const float*)d_in[3];
    const float* V1b   = (const float*)d_in[4];
    const float* V2w   = (const float*)d_in[5];
    const float* V2b   = (const float*)d_in[6];
    const float* Uw    = (const float*)d_in[7];
    const float* Ub    = (const float*)d_in[8];

    f16x8* WfH = (f16x8*)d_ws;                 // 65536 * 16 B = 1 MiB
    f16x8* WfL = WfH + 65536;                  // second 1 MiB
    float* logits = (float*)d_out;

    hipFuncSetAttribute((const void*)ntn_main,
                        hipFuncAttributeMaxDynamicSharedMemorySize, SMEM_BYTES);

    prep_w<<<256, 256, 0, stream>>>(W, WfH, WfL);
    ntn_main<<<dim3(NK, NB / 2), 256, SMEM_BYTES, stream>>>(
        texts, WfH, WfL, Wb, V1w, V1b, V2w, V2b, Uw, Ub, logits);
    softmax_rows<<<NB * NF, 64, 0, stream>>>(logits);
}